// Round 7
// baseline (160.164 us; speedup 1.0000x reference)
//
#include <hip/hip_runtime.h>

// NumericalBiasModule: out[e] = b2 + W2 · relu(W1 · rel(x[src], x[dst]) + b1)
// rel = [ratio | log_ratio | abs_diff | rel_diff], 128 features.
//
// MFMA formulation (validated r4-r6): 16 edges per wave-tile,
// mfma_f32_16x16x32_bf16. lane = (m=lane&15 edge, q=lane>>4 k-chunk);
// A-frag[j] = feat[m][q*8+j]; C/D: col=lane&15, row=q*4+reg.
// Ratio K-block uses bf16 hi/lo split on A and W (dyn range ~3e6 -> absmax ~2).
//
// Round-7 changes (r6 was gather-traffic + occupancy bound: FETCH 200MB,
// VALUBusy 38%, Occupancy 19%):
//  1. lx precompute DROPPED -- the two extra random 128B lines per edge cost
//     more than 16 quarter-rate v_log on a 38%-busy VALU. log_ratio computed
//     per edge in fp32, packed to one bf16 K-block (r4 lineage, absmax 2.0).
//     -> per-edge gather traffic halves (4 lines -> 2), one fewer weight
//     fragment set resident (5 sets = 80 VGPRs).
//  2. Grid 1024 -> 2048 blocks: register-limited residency (~2-3 waves/SIMD
//     from the unified VGPR+AGPR budget) needs more queued blocks to keep
//     CUs populated; 7.6 tiles/wave keeps W-setup overhead ~12%.
//  3. 1-deep gather pipeline kept (idx 2 ahead, x gathers 1 ahead).

#define DD    32
#define HID   64
#define RELF  128
#define EPSF  1e-8f

typedef short  bf16x8 __attribute__((ext_vector_type(8)));
typedef float  f32x4  __attribute__((ext_vector_type(4)));

union U8 { unsigned u[4]; bf16x8 v; };

static __device__ __forceinline__ unsigned pk_tr(float lo, float hi) {
    return __builtin_amdgcn_perm(__builtin_bit_cast(unsigned, hi),
                                 __builtin_bit_cast(unsigned, lo), 0x07060302u);
}
static __device__ __forceinline__ unsigned rne_bits(float f) {
    unsigned u = __builtin_bit_cast(unsigned, f);
    return u + 0x7fffu + ((u >> 16) & 1u);
}
static __device__ __forceinline__ unsigned pk_rne(float lo, float hi) {
    return __builtin_amdgcn_perm(rne_bits(hi), rne_bits(lo), 0x07060302u);
}
static __device__ __forceinline__ float hi_f32(float f) {
    return __builtin_bit_cast(float, __builtin_bit_cast(unsigned, f) & 0xffff0000u);
}

__global__ __launch_bounds__(256, 2)
void edge_bias_mfma(const float* __restrict__ x,
                    const int*   __restrict__ ei,     // [2, E]
                    const float* __restrict__ W1,     // [64, 128]
                    const float* __restrict__ b1,
                    const float* __restrict__ W2,
                    const float* __restrict__ b2,
                    float* __restrict__ out,
                    int E)
{
    const int lane = threadIdx.x & 63;
    const int wave = (blockIdx.x * blockDim.x + threadIdx.x) >> 6;
    const int nwv  = (gridDim.x * blockDim.x) >> 6;
    const int c = lane & 15;      // edge-in-tile (A) / hid-col (C)
    const int q = lane >> 4;      // k-chunk (A,B) / row-quad (C)

    // ---- B fragments, once per kernel (5 sets x 4 ntiles x 4 VGPR) ----
    // W0 = W1 cols 0..31 (ratio, hi+lo), WL = 32..63 (log_ratio),
    // WA = 64..95 (abs_diff), WD = 96..127 (rel_diff)
    bf16x8 W0h[4], W0l[4], WLf[4], WAf[4], WDf[4];
    #pragma unroll
    for (int nt = 0; nt < 4; ++nt) {
        const float* wr = W1 + (nt * 16 + c) * RELF + q * 8;
        U8 h, l, tt;
        #pragma unroll
        for (int p = 0; p < 4; ++p) {
            float w0 = wr[2 * p], w1 = wr[2 * p + 1];
            h.u[p] = pk_tr(w0, w1);
            l.u[p] = pk_rne(w0 - hi_f32(w0), w1 - hi_f32(w1));
        }
        W0h[nt] = h.v; W0l[nt] = l.v;
        #pragma unroll
        for (int p = 0; p < 4; ++p)
            tt.u[p] = pk_rne(wr[32 + 2 * p], wr[32 + 2 * p + 1]);
        WLf[nt] = tt.v;
        #pragma unroll
        for (int p = 0; p < 4; ++p)
            tt.u[p] = pk_rne(wr[64 + 2 * p], wr[64 + 2 * p + 1]);
        WAf[nt] = tt.v;
        #pragma unroll
        for (int p = 0; p < 4; ++p)
            tt.u[p] = pk_rne(wr[96 + 2 * p], wr[96 + 2 * p + 1]);
        WDf[nt] = tt.v;
    }
    float b1v[4], w2v[4];
    #pragma unroll
    for (int nt = 0; nt < 4; ++nt) {
        b1v[nt] = b1[nt * 16 + c];
        w2v[nt] = W2[nt * 16 + c];
    }
    const float b2s = b2[0];

    const int ntiles = (E + 15) >> 4;
    int t = wave;
    if (t >= ntiles) return;

    // ---- pipeline state: data(t) in flight, idx(t+nwv) resident ----
    float4 xi0C, xi1C, xj0C, xj1C;
    int srcN, dstN;

    {   // prologue: gathers for tile t
        int em = (t << 4) + c; if (em > E - 1) em = E - 1;
        int s = ei[em], d = ei[E + em];
        const float* pi = x + (long)s * DD + q * 8;
        const float* pj = x + (long)d * DD + q * 8;
        xi0C = ((const float4*)pi)[0]; xi1C = ((const float4*)pi)[1];
        xj0C = ((const float4*)pj)[0]; xj1C = ((const float4*)pj)[1];
    }
    {   // prologue: idx for tile t+nwv
        int t1 = t + nwv; if (t1 >= ntiles) t1 = t;
        int em = (t1 << 4) + c; if (em > E - 1) em = E - 1;
        srcN = ei[em]; dstN = ei[E + em];
    }

    for (; t < ntiles; t += nwv) {
        // 1. issue gathers for t+nwv (idx already resident)
        float4 xi0N, xi1N, xj0N, xj1N;
        {
            const float* pi = x + (long)srcN * DD + q * 8;
            const float* pj = x + (long)dstN * DD + q * 8;
            xi0N = ((const float4*)pi)[0]; xi1N = ((const float4*)pi)[1];
            xj0N = ((const float4*)pj)[0]; xj1N = ((const float4*)pj)[1];
        }
        // 2. load idx for t+2*nwv
        int srcN2, dstN2;
        {
            int t2 = t + 2 * nwv; if (t2 >= ntiles) t2 = t;
            int em = (t2 << 4) + c; if (em > E - 1) em = E - 1;
            srcN2 = ei[em]; dstN2 = ei[E + em];
        }

        // 3. compute tile t
        const int e0 = t << 4;
        float xiv[8] = {xi0C.x, xi0C.y, xi0C.z, xi0C.w, xi1C.x, xi1C.y, xi1C.z, xi1C.w};
        float xjv[8] = {xj0C.x, xj0C.y, xj0C.z, xj0C.w, xj1C.x, xj1C.y, xj1C.z, xj1C.w};

        U8 R, Rl, Aa, Dd, L;
        #pragma unroll
        for (int p = 0; p < 4; ++p) {
            float a0 = xiv[2*p], a1 = xiv[2*p+1];
            float c0 = xjv[2*p], c1 = xjv[2*p+1];
            // log_ratio (fp32 per edge, bf16 pack; |lr| <= ~37)
            float l0 = __logf(a0 + EPSF) - __logf(c0 + EPSF);
            float l1 = __logf(a1 + EPSF) - __logf(c1 + EPSF);
            float r0 = a0 * __builtin_amdgcn_rcpf(c0 + EPSF);
            float r1 = a1 * __builtin_amdgcn_rcpf(c1 + EPSF);
            float d0 = fabsf(a0 - c0), d1 = fabsf(a1 - c1);
            float g0 = d0 * __builtin_amdgcn_rcpf(fmaxf(a0, c0) + EPSF);
            float g1 = d1 * __builtin_amdgcn_rcpf(fmaxf(a1, c1) + EPSF);
            L.u[p]  = pk_tr(l0, l1);
            R.u[p]  = pk_tr(r0, r1);
            Rl.u[p] = pk_tr(r0 - hi_f32(r0), r1 - hi_f32(r1));
            Aa.u[p] = pk_tr(d0, d1);
            Dd.u[p] = pk_tr(g0, g1);
        }

        // ---- layer 1: 24 mfma ----
        f32x4 acc[4];
        #pragma unroll
        for (int nt = 0; nt < 4; ++nt) {
            acc[nt][0] = b1v[nt]; acc[nt][1] = b1v[nt];
            acc[nt][2] = b1v[nt]; acc[nt][3] = b1v[nt];
        }
        #pragma unroll
        for (int nt = 0; nt < 4; ++nt) {
            acc[nt] = __builtin_amdgcn_mfma_f32_16x16x32_bf16(R.v,  W0h[nt], acc[nt], 0, 0, 0);
            acc[nt] = __builtin_amdgcn_mfma_f32_16x16x32_bf16(Rl.v, W0h[nt], acc[nt], 0, 0, 0);
            acc[nt] = __builtin_amdgcn_mfma_f32_16x16x32_bf16(R.v,  W0l[nt], acc[nt], 0, 0, 0);
            acc[nt] = __builtin_amdgcn_mfma_f32_16x16x32_bf16(L.v,  WLf[nt], acc[nt], 0, 0, 0);
            acc[nt] = __builtin_amdgcn_mfma_f32_16x16x32_bf16(Aa.v, WAf[nt], acc[nt], 0, 0, 0);
            acc[nt] = __builtin_amdgcn_mfma_f32_16x16x32_bf16(Dd.v, WDf[nt], acc[nt], 0, 0, 0);
        }

        // ---- layer 2 + reduce: lane holds h[edge=q*4+r][hid=nt*16+c] ----
        float p[4];
        #pragma unroll
        for (int r = 0; r < 4; ++r) {
            float pp = 0.f;
            #pragma unroll
            for (int nt = 0; nt < 4; ++nt)
                pp = fmaf(fmaxf(acc[nt][r], 0.f), w2v[nt], pp);
            pp += __shfl_xor(pp, 1);
            pp += __shfl_xor(pp, 2);
            pp += __shfl_xor(pp, 4);
            pp += __shfl_xor(pp, 8);
            p[r] = pp;
        }
        if (c < 4) {
            const int e = e0 + q * 4 + c;
            if (e < E) {
                float v = (c == 0) ? p[0] : (c == 1) ? p[1] : (c == 2) ? p[2] : p[3];
                out[e] = v + b2s;
            }
        }

        // 4. rotate pipeline
        xi0C = xi0N; xi1C = xi1N; xj0C = xj0N; xj1C = xj1N;
        srcN = srcN2; dstN = dstN2;
    }
}

extern "C" void kernel_launch(void* const* d_in, const int* in_sizes, int n_in,
                              void* d_out, int out_size, void* d_ws, size_t ws_size,
                              hipStream_t stream)
{
    const float* x   = (const float*)d_in[0];
    const int*   ei  = (const int*)  d_in[1];
    const float* W1  = (const float*)d_in[2];
    const float* b1  = (const float*)d_in[3];
    const float* W2  = (const float*)d_in[4];
    const float* b2  = (const float*)d_in[5];
    float* out = (float*)d_out;

    const int E = out_size;  // 1,000,000
    // 2048 blocks = 8192 waves: enough queued blocks to keep the
    // register-limited residency (~2-3 waves/SIMD) saturated; ~7.6 tiles/wave
    // keeps the once-per-wave W-fragment setup at ~12% overhead.
    edge_bias_mfma<<<2048, 256, 0, stream>>>(x, ei, W1, b1, W2, b2, out, E);
}

// Round 8
// 147.556 us; speedup vs baseline: 1.0854x; 1.0854x over previous
//
#include <hip/hip_runtime.h>

// NumericalBiasModule: out[e] = b2 + W2 · relu(W1 · rel(x[src], x[dst]) + b1)
// rel = [ratio | log_ratio | abs_diff | rel_diff], 128 features.
//
// MFMA formulation (validated r4-r6): 16 edges per wave-tile,
// mfma_f32_16x16x32_bf16. lane = (m=lane&15 edge, q=lane>>4 k-chunk);
// A-frag[j] = feat[m][q*8+j]; C/D: col=lane&15, row=q*4+reg.
// Ratio K-block uses bf16 hi/lo split on A and W. log(x+eps) precomputed
// per node as bf16 (prep kernel); log_ratio = lxi·W + lxj·(-W) via linearity.
// 28 mfma/tile. absmax lineage: 2.0 (threshold 348).
//
// Round-8 change (r6/r7 A-B showed latency-bound, not traffic-bound:
// halving FETCH made it SLOWER by lengthening the serial chain):
//   depth-2 gather pipeline -- tile T's 6 gather loads issue two computes
//   before consumption (12 loads in flight/wave). At the register-pinned
//   ~2 waves/SIMD this doubles tiles-in-flight per SIMD.
//   Explicit A/B slot variables + doubled loop body: no arrays (alloca),
//   no register-rotation moves.

#define DD    32
#define HID   64
#define RELF  128
#define EPSF  1e-8f

typedef short  bf16x8 __attribute__((ext_vector_type(8)));
typedef float  f32x4  __attribute__((ext_vector_type(4)));

union U8 { unsigned u[4]; bf16x8 v; };

static __device__ __forceinline__ unsigned pk_tr(float lo, float hi) {
    return __builtin_amdgcn_perm(__builtin_bit_cast(unsigned, hi),
                                 __builtin_bit_cast(unsigned, lo), 0x07060302u);
}
static __device__ __forceinline__ unsigned rne_bits(float f) {
    unsigned u = __builtin_bit_cast(unsigned, f);
    return u + 0x7fffu + ((u >> 16) & 1u);
}
static __device__ __forceinline__ unsigned pk_rne(float lo, float hi) {
    return __builtin_amdgcn_perm(rne_bits(hi), rne_bits(lo), 0x07060302u);
}
static __device__ __forceinline__ float hi_f32(float f) {
    return __builtin_bit_cast(float, __builtin_bit_cast(unsigned, f) & 0xffff0000u);
}

__global__ __launch_bounds__(256)
void prep_logx(const float* __restrict__ x, unsigned* __restrict__ lx, int nq)
{
    int i = blockIdx.x * blockDim.x + threadIdx.x;
    if (i >= nq) return;
    float4 v = ((const float4*)x)[i];
    uint2 o;
    o.x = pk_rne(__logf(v.x + EPSF), __logf(v.y + EPSF));
    o.y = pk_rne(__logf(v.z + EPSF), __logf(v.w + EPSF));
    ((uint2*)lx)[i] = o;
}

template <int PRE>
__global__ __launch_bounds__(256, 2)
void edge_bias_mfma(const float* __restrict__ x,
                    const int*   __restrict__ ei,     // [2, E]
                    const float* __restrict__ W1,     // [64, 128]
                    const float* __restrict__ b1,
                    const float* __restrict__ W2,
                    const float* __restrict__ b2,
                    const short* __restrict__ lx,     // [N, 32] bf16 log(x+eps)
                    float* __restrict__ out,
                    int E)
{
    const int lane = threadIdx.x & 63;
    const int wave = (blockIdx.x * blockDim.x + threadIdx.x) >> 6;
    const int nwv  = (gridDim.x * blockDim.x) >> 6;
    const int c = lane & 15;      // edge-in-tile (A) / hid-col (C)
    const int q = lane >> 4;      // k-chunk (A,B) / row-quad (C)

    // ---- B fragments, once per kernel (6 sets x 4 ntiles x 4 VGPR) ----
    bf16x8 W0h[4], W0l[4], WL[4], WLn[4], WA[4], WDm[4];
    #pragma unroll
    for (int nt = 0; nt < 4; ++nt) {
        const float* wr = W1 + (nt * 16 + c) * RELF + q * 8;
        U8 h, l, tt;
        #pragma unroll
        for (int p = 0; p < 4; ++p) {
            float w0 = wr[2 * p], w1 = wr[2 * p + 1];
            h.u[p] = pk_tr(w0, w1);
            l.u[p] = pk_rne(w0 - hi_f32(w0), w1 - hi_f32(w1));
        }
        W0h[nt] = h.v; W0l[nt] = l.v;
        #pragma unroll
        for (int p = 0; p < 4; ++p)
            tt.u[p] = pk_rne(wr[32 + 2 * p], wr[32 + 2 * p + 1]);
        WL[nt] = tt.v;
        #pragma unroll
        for (int p = 0; p < 4; ++p) tt.u[p] ^= 0x80008000u;   // negate bf16 pair
        WLn[nt] = tt.v;
        #pragma unroll
        for (int p = 0; p < 4; ++p)
            tt.u[p] = pk_rne(wr[64 + 2 * p], wr[64 + 2 * p + 1]);
        WA[nt] = tt.v;
        #pragma unroll
        for (int p = 0; p < 4; ++p)
            tt.u[p] = pk_rne(wr[96 + 2 * p], wr[96 + 2 * p + 1]);
        WDm[nt] = tt.v;
    }
    float b1v[4], w2v[4];
    #pragma unroll
    for (int nt = 0; nt < 4; ++nt) {
        b1v[nt] = b1[nt * 16 + c];
        w2v[nt] = W2[nt * 16 + c];
    }
    const float b2s = b2[0];

    const int ntiles = (E + 15) >> 4;
    int t = wave;
    if (t >= ntiles) return;

    auto ldidx = [&](int tt, int& s, int& d) {
        if (tt >= ntiles) tt = t;                 // clamp to a valid tile
        int em = (tt << 4) + c; if (em > E - 1) em = E - 1;
        s = ei[em]; d = ei[E + em];
    };
    auto gather = [&](int s, int d, float4& A0, float4& A1,
                      float4& B0, float4& B1, bf16x8& Li, bf16x8& Lj) {
        const float* pi = x + (long)s * DD + q * 8;
        const float* pj = x + (long)d * DD + q * 8;
        A0 = ((const float4*)pi)[0]; A1 = ((const float4*)pi)[1];
        B0 = ((const float4*)pj)[0]; B1 = ((const float4*)pj)[1];
        if constexpr (PRE) {
            Li = *(const bf16x8*)(lx + (long)s * DD + q * 8);
            Lj = *(const bf16x8*)(lx + (long)d * DD + q * 8);
        } else { (void)Li; (void)Lj; }
    };

    auto compute = [&](int tc, float4 xi0, float4 xi1, float4 xj0, float4 xj1,
                       bf16x8 aLi, bf16x8 aLj) {
        const int e0 = tc << 4;
        float xiv[8] = {xi0.x, xi0.y, xi0.z, xi0.w, xi1.x, xi1.y, xi1.z, xi1.w};
        float xjv[8] = {xj0.x, xj0.y, xj0.z, xj0.w, xj1.x, xj1.y, xj1.z, xj1.w};

        if constexpr (!PRE) {
            U8 ti, tj;
            #pragma unroll
            for (int p = 0; p < 4; ++p) {
                ti.u[p] = pk_rne(__logf(xiv[2*p] + EPSF), __logf(xiv[2*p+1] + EPSF));
                tj.u[p] = pk_rne(__logf(xjv[2*p] + EPSF), __logf(xjv[2*p+1] + EPSF));
            }
            aLi = ti.v; aLj = tj.v;
        }

        U8 R, Rl, Aa, Dd;
        #pragma unroll
        for (int p = 0; p < 4; ++p) {
            float a0 = xiv[2*p], a1 = xiv[2*p+1];
            float c0 = xjv[2*p], c1 = xjv[2*p+1];
            float r0 = a0 * __builtin_amdgcn_rcpf(c0 + EPSF);
            float r1 = a1 * __builtin_amdgcn_rcpf(c1 + EPSF);
            float d0 = fabsf(a0 - c0), d1 = fabsf(a1 - c1);
            float g0 = d0 * __builtin_amdgcn_rcpf(fmaxf(a0, c0) + EPSF);
            float g1 = d1 * __builtin_amdgcn_rcpf(fmaxf(a1, c1) + EPSF);
            R.u[p]  = pk_tr(r0, r1);
            Rl.u[p] = pk_tr(r0 - hi_f32(r0), r1 - hi_f32(r1));
            Aa.u[p] = pk_tr(d0, d1);
            Dd.u[p] = pk_tr(g0, g1);
        }

        f32x4 acc[4];
        #pragma unroll
        for (int nt = 0; nt < 4; ++nt) {
            acc[nt][0] = b1v[nt]; acc[nt][1] = b1v[nt];
            acc[nt][2] = b1v[nt]; acc[nt][3] = b1v[nt];
        }
        #pragma unroll
        for (int nt = 0; nt < 4; ++nt) {
            acc[nt] = __builtin_amdgcn_mfma_f32_16x16x32_bf16(R.v,  W0h[nt], acc[nt], 0, 0, 0);
            acc[nt] = __builtin_amdgcn_mfma_f32_16x16x32_bf16(Rl.v, W0h[nt], acc[nt], 0, 0, 0);
            acc[nt] = __builtin_amdgcn_mfma_f32_16x16x32_bf16(R.v,  W0l[nt], acc[nt], 0, 0, 0);
            acc[nt] = __builtin_amdgcn_mfma_f32_16x16x32_bf16(aLi,  WL[nt],  acc[nt], 0, 0, 0);
            acc[nt] = __builtin_amdgcn_mfma_f32_16x16x32_bf16(aLj,  WLn[nt], acc[nt], 0, 0, 0);
            acc[nt] = __builtin_amdgcn_mfma_f32_16x16x32_bf16(Aa.v, WA[nt],  acc[nt], 0, 0, 0);
            acc[nt] = __builtin_amdgcn_mfma_f32_16x16x32_bf16(Dd.v, WDm[nt], acc[nt], 0, 0, 0);
        }

        float p[4];
        #pragma unroll
        for (int r = 0; r < 4; ++r) {
            float pp = 0.f;
            #pragma unroll
            for (int nt = 0; nt < 4; ++nt)
                pp = fmaf(fmaxf(acc[nt][r], 0.f), w2v[nt], pp);
            pp += __shfl_xor(pp, 1);
            pp += __shfl_xor(pp, 2);
            pp += __shfl_xor(pp, 4);
            pp += __shfl_xor(pp, 8);
            p[r] = pp;
        }
        if (c < 4) {
            const int e = e0 + q * 4 + c;
            if (e < E) {
                float v = (c == 0) ? p[0] : (c == 1) ? p[1] : (c == 2) ? p[2] : p[3];
                out[e] = v + b2s;
            }
        }
    };

    // ---- depth-2 pipeline: slots A (tile t) and B (tile t+nwv) ----
    float4 xA0, xA1, xA2, xA3; bf16x8 lA0, lA1;
    float4 xB0, xB1, xB2, xB3; bf16x8 lB0, lB1;
    int sC, dC;

    { int s, d; ldidx(t,           s, d); gather(s, d, xA0, xA1, xA2, xA3, lA0, lA1); }
    { int s, d; ldidx(t + nwv,     s, d); gather(s, d, xB0, xB1, xB2, xB3, lB0, lB1); }
    ldidx(t + 2 * nwv, sC, dC);

    for (;;) {
        compute(t, xA0, xA1, xA2, xA3, lA0, lA1);
        gather(sC, dC, xA0, xA1, xA2, xA3, lA0, lA1);   // tile t+2*nwv
        ldidx(t + 3 * nwv, sC, dC);
        t += nwv; if (t >= ntiles) break;

        compute(t, xB0, xB1, xB2, xB3, lB0, lB1);
        gather(sC, dC, xB0, xB1, xB2, xB3, lB0, lB1);   // tile t+2*nwv
        ldidx(t + 3 * nwv, sC, dC);
        t += nwv; if (t >= ntiles) break;
    }
}

extern "C" void kernel_launch(void* const* d_in, const int* in_sizes, int n_in,
                              void* d_out, int out_size, void* d_ws, size_t ws_size,
                              hipStream_t stream)
{
    const float* x   = (const float*)d_in[0];
    const int*   ei  = (const int*)  d_in[1];
    const float* W1  = (const float*)d_in[2];
    const float* b1  = (const float*)d_in[3];
    const float* W2  = (const float*)d_in[4];
    const float* b2  = (const float*)d_in[5];
    float* out = (float*)d_out;

    const int E  = out_size;       // 1,000,000
    const int Nd = in_sizes[0];    // N*D = 3,200,000
    short* lx = (short*)d_ws;

    const bool pre = ws_size >= (size_t)Nd * sizeof(short) && (Nd % 4) == 0;
    if (pre) {
        const int nq = Nd / 4;
        prep_logx<<<(nq + 255) / 256, 256, 0, stream>>>(x, (unsigned*)lx, nq);
        edge_bias_mfma<1><<<1024, 256, 0, stream>>>(x, ei, W1, b1, W2, b2, lx, out, E);
    } else {
        edge_bias_mfma<0><<<1024, 256, 0, stream>>>(x, ei, W1, b1, W2, b2, lx, out, E);
    }
}